// Round 5
// baseline (181.336 us; speedup 1.0000x reference)
//
#include <hip/hip_runtime.h>
#include <math.h>

#define NB 16
#define NC 64
#define NT 4096
#define NDEC 128

// alpha = exp(-1/5) in fp64, rounded to fp32 (matches reference numerics)
#define ALPHA_F 0.81873075307798185867f
#define ONEMA_F 0.18126924692201814133f
// alpha^16 = exp(-3.2)  (per-thread-segment decay)
#define Q16_F   0.040762203978366216f

// Barrier that waits LDS ops only — deliberately does NOT drain vmcnt, so
// in-flight dd global stores keep draining across the scan phase.
#define LGKM_BARRIER() asm volatile("s_waitcnt lgkmcnt(0)\n\ts_barrier" ::: "memory")

// Fused single dispatch. One block per (b,c):
//   phase A: convs + float4 dd stores (full-line coalesced) + reduced sum->LDS
//   phase B: LIF scan (16/thread, wave shuffle-scan, q^64==0 carry shortcut)
//   each block writes its own true_lat + act; last-arriving block (acq_rel
//   atomic on d_ws counter) runs the MLP head for all 16 batches.
// out layout: [pred 1024 | true_lat 1024 | act 1024 | dd 16M]
__global__ __launch_bounds__(256) void conv_lif_fused(
    const float* __restrict__ x,
    const float* __restrict__ w3, const float* __restrict__ b3,
    const float* __restrict__ w5, const float* __restrict__ b5,
    const float* __restrict__ rw, const float* __restrict__ rb,
    const float* __restrict__ lat_scale,
    const float* __restrict__ og,
    const float* __restrict__ w1, const float* __restrict__ b1,
    const float* __restrict__ w2, const float* __restrict__ b2,
    float* __restrict__ out, int* __restrict__ counter)
{
    __shared__ __align__(16) float s_x[4 + NT + 4];   // zero pad 4 each side
    __shared__ float s_sum[NT + 256];                 // +1 pad per 16 floats
    __shared__ float s_part[4];
    __shared__ int   s_wmin[4];
    __shared__ int   s_is_last;

    const int bc  = blockIdx.x;
    const int c   = bc & (NC - 1);
    const int tid = threadIdx.x;
    const int lane = tid & 63;

    // ---- stage x row into LDS (float4, coalesced) ----
    if (tid < 4) { s_x[tid] = 0.f; s_x[4 + NT + tid] = 0.f; }
    {
        const float4* x4  = (const float4*)(x + (size_t)bc * NT);
        float4*       sx4 = (float4*)(s_x + 4);
        #pragma unroll
        for (int i = 0; i < 4; ++i) sx4[i * 256 + tid] = x4[i * 256 + tid];
    }

    // ---- per-channel weights (block-uniform scalar loads) ----
    const float w30a = w3[(c*2+0)*3+0], w30b = w3[(c*2+0)*3+1], w30c = w3[(c*2+0)*3+2];
    const float w31a = w3[(c*2+1)*3+0], w31b = w3[(c*2+1)*3+1], w31c = w3[(c*2+1)*3+2];
    const float b30 = b3[c*2+0], b31 = b3[c*2+1];
    const float* w50p = w5 + (c*2+0)*5;
    const float* w51p = w5 + (c*2+1)*5;
    const float w50a=w50p[0], w50b=w50p[1], w50c=w50p[2], w50d=w50p[3], w50e=w50p[4];
    const float w51a=w51p[0], w51b=w51p[1], w51c=w51p[2], w51d=w51p[3], w51e=w51p[4];
    const float b50 = b5[c*2+0], b51 = b5[c*2+1];
    const float rw0 = rw[c*4+0], rw1 = rw[c*4+1], rw2 = rw[c*4+2], rw3 = rw[c*4+3];
    const float rbc = rb[c];

    __syncthreads();   // staging: global->LDS writes must be visible

    // ---- phase A: convs; float4 dd stores; reduced sum -> padded LDS ----
    float* dd = out + 3072 + (size_t)bc * (4 * NT);
    #pragma unroll
    for (int i = 0; i < 4; ++i) {
        const int t = i * 1024 + tid * 4;          // 4 consecutive outputs
        const float4 c0 = *(const float4*)(s_x + t);       // x[t-4..t-1]
        const float4 c1 = *(const float4*)(s_x + t + 4);   // x[t..t+3]
        const float4 c2 = *(const float4*)(s_x + t + 8);   // x[t+4..t+7]
        const float in[8] = {c0.z, c0.w, c1.x, c1.y, c1.z, c1.w, c2.x, c2.y};
        float4 v30, v31, v50, v51;
        const int pad = t >> 4;                    // same pad block for j=0..3
        #pragma unroll
        for (int j = 0; j < 4; ++j) {
            const float xm2 = in[j], xm1 = in[j+1], x0 = in[j+2];
            const float xp1 = in[j+3], xp2 = in[j+4];
            float o30 = fmaf(w30c, xp1, fmaf(w30b, x0, fmaf(w30a, xm1, b30)));
            float o31 = fmaf(w31c, xp1, fmaf(w31b, x0, fmaf(w31a, xm1, b31)));
            float o50 = fmaf(w50e, xp2, fmaf(w50d, xp1, fmaf(w50c, x0,
                        fmaf(w50b, xm1, fmaf(w50a, xm2, b50)))));
            float o51 = fmaf(w51e, xp2, fmaf(w51d, xp1, fmaf(w51c, x0,
                        fmaf(w51b, xm1, fmaf(w51a, xm2, b51)))));
            ((float*)&v30)[j] = o30;
            ((float*)&v31)[j] = o31;
            ((float*)&v50)[j] = o50;
            ((float*)&v51)[j] = o51;
            s_sum[t + j + pad] = fmaf(rw3, o51, fmaf(rw2, o50,
                                 fmaf(rw1, o31, fmaf(rw0, o30, rbc))));
        }
        *(float4*)(dd + t)          = v30;
        *(float4*)(dd + NT + t)     = v31;
        *(float4*)(dd + 2 * NT + t) = v50;
        *(float4*)(dd + 3 * NT + t) = v51;
    }
    // only s_sum needs protecting — dd stores stay in flight
    LGKM_BARRIER();

    // ---- phase B: LIF scan. thread owns t in [tid*16, tid*16+16) ----
    const int t0 = tid * 16;
    float dv[16];
    #pragma unroll
    for (int j = 0; j < 16; ++j) dv[j] = s_sum[t0 + tid + j];  // padded index

    float V = 0.f;
    #pragma unroll
    for (int j = 0; j < 16; ++j)
        V = __fadd_rn(__fmul_rn(ALPHA_F, V), __fmul_rn(ONEMA_F, dv[j]));

    // wave-level inclusive scan, coefficient q = alpha^16 (q^32==0 in fp32)
    float S = V;
    float coef = Q16_F;
    #pragma unroll
    for (int off = 1; off <= 16; off <<= 1) {
        float p = __shfl_up(S, off);
        if (lane >= off) S = fmaf(coef, p, S);
        coef *= coef;
    }

    // cross-wave carry: q^64 == 0 => only previous wave's partial matters
    if (lane == 63) s_part[tid >> 6] = S;
    LGKM_BARRIER();
    const float Pprev = (tid >= 64) ? s_part[(tid >> 6) - 1] : 0.f;

    // q^lane via exact repeated squaring
    float ql = 1.f, qp = Q16_F;
    #pragma unroll
    for (int bit = 0; bit < 6; ++bit) {
        if ((lane >> bit) & 1) ql *= qp;
        qp *= qp;
    }

    // exclusive prefix, then re-run segment for first threshold crossing
    float Sm1 = __shfl_up(S, 1);
    float V2 = fmaf(Pprev, ql, (lane > 0) ? Sm1 : 0.f);
    int firstt = NT;
    #pragma unroll
    for (int j = 0; j < 16; ++j) {
        V2 = __fadd_rn(__fmul_rn(ALPHA_F, V2), __fmul_rn(ONEMA_F, dv[j]));
        if (V2 >= 1.0f && firstt == NT) firstt = t0 + j;
    }

    int m = firstt;
    #pragma unroll
    for (int off = 32; off > 0; off >>= 1) m = min(m, __shfl_down(m, off));
    if (lane == 0) s_wmin[tid >> 6] = m;
    LGKM_BARRIER();

    if (tid == 0) {
        int r = min(min(s_wmin[0], s_wmin[1]), min(s_wmin[2], s_wmin[3]));
        float tl = (float)r;
        out[1024 + bc] = tl;                                  // true_latency
        const float scale = fmaxf(lat_scale[0], 0.001f);
        out[2048 + bc] = expf(-tl / scale);                   // act
        // release this block's out writes, count arrivals (agent scope)
        int prev = __hip_atomic_fetch_add(counter, 1, __ATOMIC_ACQ_REL,
                                          __HIP_MEMORY_SCOPE_AGENT);
        s_is_last = (prev == (int)(NB * NC) - 1);
    }
    __syncthreads();
    if (!s_is_last) return;   // non-tail blocks exit; dd stores drain at endpgm

    // ================= tail block: MLP head for all 16 batches =============
    // acq_rel RMW chain on `counter` gives happens-before with every block.
    float* s_act   = s_x;            // alias: phases A/B complete
    float* s_mixed = s_x + 1024;
    float* s_h     = s_sum;          // 2048 floats

    const float scale = fmaxf(lat_scale[0], 0.001f);

    #pragma unroll
    for (int k = tid; k < 1024; k += 256) {
        float tl = out[1024 + k];
        s_act[k] = expf(-tl / scale);
    }
    __syncthreads();

    #pragma unroll
    for (int k = tid; k < 1024; k += 256) {       // mixed = act @ og^T
        int b = k >> 6, cc0 = k & 63;
        const float* ob = og + cc0 * NC;
        const float* ab = s_act + b * NC;
        float mx = 0.f;
        #pragma unroll 8
        for (int cc = 0; cc < NC; ++cc) mx = fmaf(ab[cc], ob[cc], mx);
        s_mixed[k] = mx;
    }
    __syncthreads();

    #pragma unroll
    for (int k = tid; k < 2048; k += 256) {       // h = relu(mixed @ w1^T + b1)
        int b = k >> 7, j = k & 127;
        const float* mb = s_mixed + b * NC;
        const float* wj = w1 + j * NC;
        float h = b1[j];
        #pragma unroll 8
        for (int i = 0; i < NC; ++i) h = fmaf(mb[i], wj[i], h);
        s_h[k] = fmaxf(h, 0.f);
    }
    __syncthreads();

    #pragma unroll
    for (int k = tid; k < 1024; k += 256) {       // pred = clip(softplus(...))
        int b = k >> 6, cc0 = k & 63;
        const float* hb = s_h + b * NDEC;
        const float* wc = w2 + cc0 * NDEC;
        float r = b2[cc0];
        #pragma unroll 8
        for (int j = 0; j < NDEC; ++j) r = fmaf(hb[j], wc[j], r);
        float sp = fmaxf(r, 0.f) + log1pf(expf(-fabsf(r)));
        out[k] = fminf(sp, (float)NT);
    }
}

extern "C" void kernel_launch(void* const* d_in, const int* in_sizes, int n_in,
                              void* d_out, int out_size, void* d_ws, size_t ws_size,
                              hipStream_t stream) {
    const float* x  = (const float*)d_in[0];
    const float* w3 = (const float*)d_in[1];
    const float* b3 = (const float*)d_in[2];
    const float* w5 = (const float*)d_in[3];
    const float* b5 = (const float*)d_in[4];
    const float* rw = (const float*)d_in[5];
    const float* rb = (const float*)d_in[6];
    const float* ls = (const float*)d_in[7];
    const float* og = (const float*)d_in[8];
    const float* w1 = (const float*)d_in[9];
    const float* b1 = (const float*)d_in[10];
    const float* w2 = (const float*)d_in[11];
    const float* b2 = (const float*)d_in[12];
    float* out = (float*)d_out;
    int* counter = (int*)d_ws;

    hipMemsetAsync(counter, 0, sizeof(int), stream);   // graph-capturable node
    conv_lif_fused<<<NB * NC, 256, 0, stream>>>(
        x, w3, b3, w5, b5, rw, rb, ls, og, w1, b1, w2, b2, out, counter);
}

// Round 6
// 120.171 us; speedup vs baseline: 1.5090x; 1.5090x over previous
//
#include <hip/hip_runtime.h>
#include <math.h>

#define NB 16
#define NC 64
#define NT 4096
#define NDEC 128

// alpha = exp(-1/5) in fp64, rounded to fp32 (matches reference numerics)
#define ALPHA_F 0.81873075307798185867f
#define ONEMA_F 0.18126924692201814133f
// alpha^16 = exp(-3.2)  (per-thread-segment decay)
#define Q16_F   0.040762203978366216f

// Barrier that waits LDS ops only — deliberately does NOT drain vmcnt, so
// in-flight dd global stores keep draining across the scan phase.
#define LGKM_BARRIER() asm volatile("s_waitcnt lgkmcnt(0)\n\ts_barrier" ::: "memory")

// One block per (b,c). No x staging (direct global reads, L1/L2-absorbed
// overlap) => LDS 17.4 KB => 8 blocks/CU, doubled outstanding-store depth.
// Phase A: convs + float4 dd stores (full-line coalesced), summed -> LDS.
// Phase B: LIF scan (16/thread, wave shuffle-scan, q^64==0 carry shortcut).
// NOTE: no device/agent-scope fences anywhere — on multi-XCD gfx950 an
// agent-scope release triggers an L2 writeback storm (R2/R5: 93us @ 10% BW).
// out layout: [pred 1024 | true_lat 1024 | act 1024 | dd 16M]
__global__ __launch_bounds__(256) void conv_lif_kernel(
    const float* __restrict__ x,
    const float* __restrict__ w3, const float* __restrict__ b3,
    const float* __restrict__ w5, const float* __restrict__ b5,
    const float* __restrict__ rw, const float* __restrict__ rb,
    float* __restrict__ out)
{
    __shared__ float s_sum[NT + 256];                 // +1 pad per 16 floats
    __shared__ float s_part[4];
    __shared__ int   s_wmin[4];

    const int bc  = blockIdx.x;
    const int c   = bc & (NC - 1);
    const int tid = threadIdx.x;
    const int lane = tid & 63;

    // ---- per-channel weights (block-uniform scalar loads) ----
    const float w30a = w3[(c*2+0)*3+0], w30b = w3[(c*2+0)*3+1], w30c = w3[(c*2+0)*3+2];
    const float w31a = w3[(c*2+1)*3+0], w31b = w3[(c*2+1)*3+1], w31c = w3[(c*2+1)*3+2];
    const float b30 = b3[c*2+0], b31 = b3[c*2+1];
    const float* w50p = w5 + (c*2+0)*5;
    const float* w51p = w5 + (c*2+1)*5;
    const float w50a=w50p[0], w50b=w50p[1], w50c=w50p[2], w50d=w50p[3], w50e=w50p[4];
    const float w51a=w51p[0], w51b=w51p[1], w51c=w51p[2], w51d=w51p[3], w51e=w51p[4];
    const float b50 = b5[c*2+0], b51 = b5[c*2+1];
    const float rw0 = rw[c*4+0], rw1 = rw[c*4+1], rw2 = rw[c*4+2], rw3 = rw[c*4+3];
    const float rbc = rb[c];

    // ---- phase A: convs from global x; float4 dd stores; summed -> LDS ----
    const float* xb = x + (size_t)bc * NT;
    float* dd = out + 3072 + (size_t)bc * (4 * NT);
    const float4 z4 = {0.f, 0.f, 0.f, 0.f};
    #pragma unroll
    for (int i = 0; i < 4; ++i) {
        const int t = i * 1024 + tid * 4;          // 4 consecutive outputs
        // x[t-4..t+7] via 3 float4 loads; clamp addr + select at row edges
        const int ta = (t == 0)    ? 0    : t - 4;
        const int tb = (t == 4092) ? 4080 : t + 4;
        float4 c0 = *(const float4*)(xb + ta);
        float4 c1 = *(const float4*)(xb + t);
        float4 c2 = *(const float4*)(xb + tb);
        if (t == 0)    c0 = z4;
        if (t == 4092) c2 = z4;
        const float in[8] = {c0.z, c0.w, c1.x, c1.y, c1.z, c1.w, c2.x, c2.y};
        float4 v30, v31, v50, v51;
        const int pad = t >> 4;                    // same pad block for j=0..3
        #pragma unroll
        for (int j = 0; j < 4; ++j) {
            const float xm2 = in[j], xm1 = in[j+1], x0 = in[j+2];
            const float xp1 = in[j+3], xp2 = in[j+4];
            float o30 = fmaf(w30c, xp1, fmaf(w30b, x0, fmaf(w30a, xm1, b30)));
            float o31 = fmaf(w31c, xp1, fmaf(w31b, x0, fmaf(w31a, xm1, b31)));
            float o50 = fmaf(w50e, xp2, fmaf(w50d, xp1, fmaf(w50c, x0,
                        fmaf(w50b, xm1, fmaf(w50a, xm2, b50)))));
            float o51 = fmaf(w51e, xp2, fmaf(w51d, xp1, fmaf(w51c, x0,
                        fmaf(w51b, xm1, fmaf(w51a, xm2, b51)))));
            ((float*)&v30)[j] = o30;
            ((float*)&v31)[j] = o31;
            ((float*)&v50)[j] = o50;
            ((float*)&v51)[j] = o51;
            s_sum[t + j + pad] = fmaf(rw3, o51, fmaf(rw2, o50,
                                 fmaf(rw1, o31, fmaf(rw0, o30, rbc))));
        }
        *(float4*)(dd + t)          = v30;
        *(float4*)(dd + NT + t)     = v31;
        *(float4*)(dd + 2 * NT + t) = v50;
        *(float4*)(dd + 3 * NT + t) = v51;
    }
    // only s_sum needs protecting — dd stores stay in flight
    LGKM_BARRIER();

    // ---- phase B: LIF scan. thread owns t in [tid*16, tid*16+16) ----
    const int t0 = tid * 16;
    float dv[16];
    #pragma unroll
    for (int j = 0; j < 16; ++j) dv[j] = s_sum[t0 + tid + j];  // padded index

    float V = 0.f;
    #pragma unroll
    for (int j = 0; j < 16; ++j)
        V = __fadd_rn(__fmul_rn(ALPHA_F, V), __fmul_rn(ONEMA_F, dv[j]));

    // wave-level inclusive scan, coefficient q = alpha^16 (q^32==0 in fp32)
    float S = V;
    float coef = Q16_F;
    #pragma unroll
    for (int off = 1; off <= 16; off <<= 1) {
        float p = __shfl_up(S, off);
        if (lane >= off) S = fmaf(coef, p, S);
        coef *= coef;
    }

    // cross-wave carry: q^64 == 0 => only previous wave's partial matters
    if (lane == 63) s_part[tid >> 6] = S;
    LGKM_BARRIER();
    const float Pprev = (tid >= 64) ? s_part[(tid >> 6) - 1] : 0.f;

    // q^lane via exact repeated squaring
    float ql = 1.f, qp = Q16_F;
    #pragma unroll
    for (int bit = 0; bit < 6; ++bit) {
        if ((lane >> bit) & 1) ql *= qp;
        qp *= qp;
    }

    // exclusive prefix, then re-run segment for first threshold crossing
    float Sm1 = __shfl_up(S, 1);
    float V2 = fmaf(Pprev, ql, (lane > 0) ? Sm1 : 0.f);
    int firstt = NT;
    #pragma unroll
    for (int j = 0; j < 16; ++j) {
        V2 = __fadd_rn(__fmul_rn(ALPHA_F, V2), __fmul_rn(ONEMA_F, dv[j]));
        if (V2 >= 1.0f && firstt == NT) firstt = t0 + j;
    }

    int m = firstt;
    #pragma unroll
    for (int off = 32; off > 0; off >>= 1) m = min(m, __shfl_down(m, off));
    if (lane == 0) s_wmin[tid >> 6] = m;
    LGKM_BARRIER();
    if (tid == 0) {
        int r = min(min(s_wmin[0], s_wmin[1]), min(s_wmin[2], s_wmin[3]));
        out[1024 + bc] = (float)r;   // true_latency (T if never fired)
    }
    // end-of-kernel implicit drain overlaps dd stores with phase B
}

// One block per batch element: act -> gates -> MLP -> softplus/clip
__global__ __launch_bounds__(128) void head_kernel(
    const float* __restrict__ lat_scale,
    const float* __restrict__ og,
    const float* __restrict__ w1, const float* __restrict__ b1,
    const float* __restrict__ w2, const float* __restrict__ b2,
    float* __restrict__ out)
{
    __shared__ float act_s[NC];
    __shared__ float mixed_s[NC];
    __shared__ float h_s[NDEC];
    const int b   = blockIdx.x;
    const int tid = threadIdx.x;
    const float scale = fmaxf(lat_scale[0], 0.001f);

    if (tid < NC) {
        float tl = out[1024 + b * NC + tid];
        float a  = expf(-tl / scale);
        act_s[tid] = a;
        out[2048 + b * NC + tid] = a;        // act output
    }
    __syncthreads();

    if (tid < NC) {
        float mx = 0.f;
        #pragma unroll 8
        for (int cc = 0; cc < NC; ++cc) mx = fmaf(act_s[cc], og[tid * NC + cc], mx);
        mixed_s[tid] = mx;
    }
    __syncthreads();

    {   // all 128 threads: hidden layer
        float h = b1[tid];
        #pragma unroll 8
        for (int i = 0; i < NC; ++i) h = fmaf(mixed_s[i], w1[tid * NC + i], h);
        h_s[tid] = fmaxf(h, 0.f);
    }
    __syncthreads();

    if (tid < NC) {
        float r = b2[tid];
        #pragma unroll 8
        for (int j = 0; j < NDEC; ++j) r = fmaf(h_s[j], w2[tid * NDEC + j], r);
        float sp = fmaxf(r, 0.f) + log1pf(expf(-fabsf(r)));
        out[b * NC + tid] = fminf(sp, (float)NT);
    }
}

extern "C" void kernel_launch(void* const* d_in, const int* in_sizes, int n_in,
                              void* d_out, int out_size, void* d_ws, size_t ws_size,
                              hipStream_t stream) {
    const float* x  = (const float*)d_in[0];
    const float* w3 = (const float*)d_in[1];
    const float* b3 = (const float*)d_in[2];
    const float* w5 = (const float*)d_in[3];
    const float* b5 = (const float*)d_in[4];
    const float* rw = (const float*)d_in[5];
    const float* rb = (const float*)d_in[6];
    const float* ls = (const float*)d_in[7];
    const float* og = (const float*)d_in[8];
    const float* w1 = (const float*)d_in[9];
    const float* b1 = (const float*)d_in[10];
    const float* w2 = (const float*)d_in[11];
    const float* b2 = (const float*)d_in[12];
    float* out = (float*)d_out;

    conv_lif_kernel<<<NB * NC, 256, 0, stream>>>(x, w3, b3, w5, b5, rw, rb, out);
    head_kernel<<<NB, 128, 0, stream>>>(ls, og, w1, b1, w2, b2, out);
}